// Round 10
// baseline (68.581 us; speedup 1.0000x reference)
//
#include <hip/hip_runtime.h>

#define DIMV 96
#define NCH 24
constexpr int VOX = DIMV * DIMV * DIMV;          // 884736
constexpr int N_CUR = 150000;
constexpr int N_GLB = 200000;
constexpr int N_TGT_LOC = 100000;
constexpr int N_TGT_GLB = 120000;

// ---- output offsets (floats) ----
constexpr size_t OFF_COORDS = 0;
constexpr size_t OFF_CURVOL = 450000;                         // 150000*3 (16B-aligned)
constexpr size_t OFF_GLBVOL = OFF_CURVOL + (size_t)VOX * NCH; // 21,683,664
constexpr size_t OFF_TGTVOL = OFF_GLBVOL + (size_t)VOX * NCH; // 42,917,328 (16B-aligned)
constexpr size_t OFF_VALID  = OFF_TGTVOL + (size_t)VOX;       // 43,802,064
constexpr size_t OFF_VALIDT = OFF_VALID + N_GLB;              // 44,002,064

typedef float v4f __attribute__((ext_vector_type(4)));
typedef int   v4i __attribute__((ext_vector_type(4)));

constexpr int N_COORD4 = (N_CUR * 3) / 4;        // 112500 int4->float4 copies
constexpr int NV4_WS   = (3 * VOX) / 4;          // 663552 int4 stores to init winners

__device__ __forceinline__ int voxel_of(int x, int y, int z) {
    return (x * DIMV + y) * DIMV + z;
}

// Kernel I: workspace winner init (-1) + coords int4->float4 copy.
// PLAIN stores (R1: NT init of the atomic-hammered winner arrays cost ~20 us).
__global__ void __launch_bounds__(256) k_init(int* __restrict__ ws,
                                              const int* __restrict__ cur_coords,
                                              float* __restrict__ coords_out) {
    int i = blockIdx.x * blockDim.x + threadIdx.x;
    if (i < NV4_WS) {
        v4i m = {-1, -1, -1, -1};
        *((v4i*)ws + i) = m;
    } else if (i < NV4_WS + N_COORD4) {
        int j = i - NV4_WS;
        v4i c = *(const v4i*)(cur_coords + 4 * j);
        v4f f = {(float)c.x, (float)c.y, (float)c.z, (float)c.w};
        *((v4f*)coords_out + j) = f;
    }
}

// Kernel W (R9, kept): {point atomics ∥ dense default fill} in ONE dispatch.
// Disjoint memory (workspace vs outputs) -> no ordering needed. Atomics at
// low block indices overlap the stream's ramp; defaults are DENSE UNMASKED
// plain v4f stores (R8: masked streams pay partial-line RMW).
constexpr int P_TOTAL = N_CUR + N_TGT_GLB + N_TGT_LOC + N_GLB;   // 570000
constexpr int Z4 = (VOX * NCH * 2) / 4;           // 10,616,832 v4f chunks (cur+glb zeros)
constexpr int T4 = VOX / 4;                       //    221,184 v4f chunks (tgt ones)
constexpr int WORK_TOTAL = P_TOTAL + Z4 + T4;

__global__ void __launch_bounds__(256) k_work(
                         const int* __restrict__ cur_coords,
                         const int* __restrict__ tgt_coords_g,
                         const int* __restrict__ tgt_coords_l,
                         const int* __restrict__ glb_coords,
                         const int* __restrict__ origin,
                         int* __restrict__ w_cur,
                         int* __restrict__ w_tgt,
                         int* __restrict__ w_glb,
                         float* __restrict__ validt_out,
                         float* __restrict__ vol_base,   // out+OFF_CURVOL (cur+glb contiguous)
                         float* __restrict__ tgt_out) {
    int i = blockIdx.x * blockDim.x + threadIdx.x;
    if (i < N_CUR) {
        int x = cur_coords[3 * i], y = cur_coords[3 * i + 1], z = cur_coords[3 * i + 2];
        if ((unsigned)x < DIMV && (unsigned)y < DIMV && (unsigned)z < DIMV)
            atomicMax(&w_cur[voxel_of(x, y, z)], i);   // last-write-wins = max idx
    } else if (i < N_CUR + N_TGT_GLB) {
        int j = i - N_CUR;
        int x = tgt_coords_g[3 * j]     - origin[0];
        int y = tgt_coords_g[3 * j + 1] - origin[1];
        int z = tgt_coords_g[3 * j + 2] - origin[2];
        bool inb = (unsigned)x < DIMV && (unsigned)y < DIMV && (unsigned)z < DIMV;
        validt_out[j] = inb ? 1.0f : 0.0f;
        if (inb) atomicMax(&w_tgt[voxel_of(x, y, z)], j);
    } else if (i < N_CUR + N_TGT_GLB + N_TGT_LOC) {
        int j = i - N_CUR - N_TGT_GLB;
        int x = tgt_coords_l[3 * j], y = tgt_coords_l[3 * j + 1], z = tgt_coords_l[3 * j + 2];
        if ((unsigned)x < DIMV && (unsigned)y < DIMV && (unsigned)z < DIMV)
            atomicMax(&w_tgt[voxel_of(x, y, z)], j + N_TGT_GLB);
    } else if (i < P_TOTAL) {
        int j = i - N_CUR - N_TGT_GLB - N_TGT_LOC;
        int x = glb_coords[3 * j]     - origin[0];
        int y = glb_coords[3 * j + 1] - origin[1];
        int z = glb_coords[3 * j + 2] - origin[2];
        if ((unsigned)x < DIMV && (unsigned)y < DIMV && (unsigned)z < DIMV)
            atomicMax(&w_glb[voxel_of(x, y, z)], j);   // occupancy gated in k_payload
    } else if (i < P_TOTAL + Z4) {
        int j = i - P_TOTAL;
        *((v4f*)vol_base + j) = (v4f){0.f, 0.f, 0.f, 0.f};
    } else if (i < WORK_TOTAL) {
        int j = i - P_TOTAL - Z4;
        *((v4f*)tgt_out + j) = (v4f){1.f, 1.f, 1.f, 1.f};
    }
}

// Kernel V (R10): VOXEL-driven masked payload over completed defaults.
// = R7's fused fill minus the default stores: linear w_* reads, gathers
// only at occupied voxels, stores in ascending-v order (DRAM-friendly,
// sparse-but-ordered — NOT R9's random point-driven scatter).
//  seg P [0, N_GLB):   per-point global `valid` (latency-bound, starts early)
//  seg V [+VOX*6):     masked winner-row writes
constexpr int PAY_TOTAL = N_GLB + VOX * 6;

__global__ void __launch_bounds__(256) k_payload(
                           const int* __restrict__ w_cur,
                           const int* __restrict__ w_glb,
                           const int* __restrict__ w_tgt,
                           const int* __restrict__ glb_coords,
                           const int* __restrict__ origin,
                           const float* __restrict__ cur_values,
                           const float* __restrict__ glb_values,
                           const float* __restrict__ glb_tsdf,   // [120000]
                           const float* __restrict__ loc_tsdf,   // [100000]
                           float* __restrict__ cur_out,
                           float* __restrict__ glb_out,
                           float* __restrict__ tgt_out,
                           float* __restrict__ valid_out) {
    int idx = blockIdx.x * blockDim.x + threadIdx.x;
    if (idx < N_GLB) {
        int x = glb_coords[3 * idx]     - origin[0];
        int y = glb_coords[3 * idx + 1] - origin[1];
        int z = glb_coords[3 * idx + 2] - origin[2];
        bool inb = (unsigned)x < DIMV && (unsigned)y < DIMV && (unsigned)z < DIMV;
        int cx = min(max(x, 0), DIMV - 1);
        int cy = min(max(y, 0), DIMV - 1);
        int cz = min(max(z, 0), DIMV - 1);
        bool valid = inb && (w_cur[voxel_of(cx, cy, cz)] >= 0);   // occ != 0
        valid_out[idx] = valid ? 1.0f : 0.0f;
        return;
    }
    idx -= N_GLB;
    if (idx >= VOX * 6) return;
    int v = idx / 6, q = idx - v * 6;

    int wc = w_cur[v];
    if (wc >= 0)
        *(v4f*)(cur_out + (size_t)v * NCH + q * 4) =
            *(const v4f*)(cur_values + (size_t)wc * NCH + q * 4);

    int wg = w_glb[v];
    if (wg >= 0 && wc >= 0)   // voxel-side occupancy gate
        *(v4f*)(glb_out + (size_t)v * NCH + q * 4) =
            *(const v4f*)(glb_values + (size_t)wg * NCH + q * 4);

    if (q == 0) {
        int wt = w_tgt[v];
        if (wt >= 0)
            tgt_out[v] = (wt < N_TGT_GLB) ? glb_tsdf[wt] : loc_tsdf[wt - N_TGT_GLB];
    }
}

extern "C" void kernel_launch(void* const* d_in, const int* in_sizes, int n_in,
                              void* d_out, int out_size, void* d_ws, size_t ws_size,
                              hipStream_t stream) {
    const int*   cur_coords   = (const int*)d_in[0];
    const float* cur_values   = (const float*)d_in[1];
    const int*   glb_coords   = (const int*)d_in[2];
    const float* glb_values   = (const float*)d_in[3];
    const int*   tgt_coords_l = (const int*)d_in[4];
    const float* tgt_tsdf_l   = (const float*)d_in[5];
    const int*   tgt_coords_g = (const int*)d_in[6];
    const float* tgt_tsdf_g   = (const float*)d_in[7];
    const int*   rel_origin   = (const int*)d_in[8];

    float* out = (float*)d_out;
    int* w_cur = (int*)d_ws;         // [VOX] winner current (>=0 also = occupancy)
    int* w_glb = w_cur + VOX;        // [VOX] winner global (in-bounds, voxel-gated)
    int* w_tgt = w_glb + VOX;        // [VOX] winner target

    const int T = 256;
    auto blocks = [](int n) { return (n + 255) / 256; };

    // 1: winner init to -1 + coords copy
    k_init<<<blocks(NV4_WS + N_COORD4), T, 0, stream>>>(
        (int*)d_ws, cur_coords, out + OFF_COORDS);

    // 2: point atomics ∥ dense default fill (disjoint memory, one dispatch)
    k_work<<<blocks(WORK_TOTAL), T, 0, stream>>>(
        cur_coords, tgt_coords_g, tgt_coords_l, glb_coords, rel_origin,
        w_cur, w_tgt, w_glb, out + OFF_VALIDT,
        out + OFF_CURVOL, out + OFF_TGTVOL);

    // 3: voxel-driven masked payload + valid (ordered after defaults)
    k_payload<<<blocks(PAY_TOTAL), T, 0, stream>>>(
        w_cur, w_glb, w_tgt, glb_coords, rel_origin,
        cur_values, glb_values, tgt_tsdf_g, tgt_tsdf_l,
        out + OFF_CURVOL, out + OFF_GLBVOL, out + OFF_TGTVOL, out + OFF_VALID);
}

// Round 11
// 55.926 us; speedup vs baseline: 1.2263x; 1.2263x over previous
//
#include <hip/hip_runtime.h>

#define DIMV 96
#define NCH 24
constexpr int VOX = DIMV * DIMV * DIMV;          // 884736
constexpr int N_CUR = 150000;
constexpr int N_GLB = 200000;
constexpr int N_TGT_LOC = 100000;
constexpr int N_TGT_GLB = 120000;

// ---- output offsets (floats) ----
constexpr size_t OFF_COORDS = 0;
constexpr size_t OFF_CURVOL = 450000;                         // 150000*3
constexpr size_t OFF_GLBVOL = OFF_CURVOL + (size_t)VOX * NCH; // 21,683,664
constexpr size_t OFF_TGTVOL = OFF_GLBVOL + (size_t)VOX * NCH; // 42,917,328
constexpr size_t OFF_VALID  = OFF_TGTVOL + (size_t)VOX;       // 43,802,064
constexpr size_t OFF_VALIDT = OFF_VALID + N_GLB;              // 44,002,064

typedef float v4f __attribute__((ext_vector_type(4)));
typedef int   v4i __attribute__((ext_vector_type(4)));

constexpr int N_COORD4 = (N_CUR * 3) / 4;        // 112500 int4->float4 copies
constexpr int NV4_WS   = (3 * VOX) / 4;          // 663552 int4 stores to init winners
constexpr int FILL_CHUNKS = VOX * 6;             // 5,308,416 16B chunks (x2 volumes)

__device__ __forceinline__ int voxel_of(int x, int y, int z) {
    return (x * DIMV + y) * DIMV + z;
}

// Kernel I: workspace winner init (-1) + coords int4->float4 copy.
// PLAIN stores (R1: NT init of the atomic-hammered winner arrays cost ~20 us).
__global__ void __launch_bounds__(256) k_init(int* __restrict__ ws,
                                              const int* __restrict__ cur_coords,
                                              float* __restrict__ coords_out) {
    int i = blockIdx.x * blockDim.x + threadIdx.x;
    if (i < NV4_WS) {
        v4i m = {-1, -1, -1, -1};
        *((v4i*)ws + i) = m;
    } else if (i < NV4_WS + N_COORD4) {
        int j = i - NV4_WS;
        v4i c = *(const v4i*)(cur_coords + 4 * j);
        v4f f = {(float)c.x, (float)c.y, (float)c.z, (float)c.w};
        *((v4f*)coords_out + j) = f;
    }
}

// Kernel P: ALL point scatters in one launch. Occupancy gating for global
// points is voxel-side (see k_fill_all): scatter every IN-BOUNDS global
// point; winner sets identical where the fill emits payload.
__global__ void k_points(const int* __restrict__ cur_coords,
                         const int* __restrict__ tgt_coords_g,
                         const int* __restrict__ tgt_coords_l,
                         const int* __restrict__ glb_coords,
                         const int* __restrict__ origin,
                         int* __restrict__ w_cur,
                         int* __restrict__ w_tgt,
                         int* __restrict__ w_glb,
                         float* __restrict__ validt_out) {
    int i = blockIdx.x * blockDim.x + threadIdx.x;
    if (i < N_CUR) {
        int x = cur_coords[3 * i], y = cur_coords[3 * i + 1], z = cur_coords[3 * i + 2];
        if ((unsigned)x < DIMV && (unsigned)y < DIMV && (unsigned)z < DIMV)
            atomicMax(&w_cur[voxel_of(x, y, z)], i);   // last-write-wins = max idx
    } else if (i < N_CUR + N_TGT_GLB) {
        int j = i - N_CUR;
        int x = tgt_coords_g[3 * j]     - origin[0];
        int y = tgt_coords_g[3 * j + 1] - origin[1];
        int z = tgt_coords_g[3 * j + 2] - origin[2];
        bool inb = (unsigned)x < DIMV && (unsigned)y < DIMV && (unsigned)z < DIMV;
        validt_out[j] = inb ? 1.0f : 0.0f;
        if (inb) atomicMax(&w_tgt[voxel_of(x, y, z)], j);
    } else if (i < N_CUR + N_TGT_GLB + N_TGT_LOC) {
        int j = i - N_CUR - N_TGT_GLB;
        int x = tgt_coords_l[3 * j], y = tgt_coords_l[3 * j + 1], z = tgt_coords_l[3 * j + 2];
        if ((unsigned)x < DIMV && (unsigned)y < DIMV && (unsigned)z < DIMV)
            atomicMax(&w_tgt[voxel_of(x, y, z)], j + N_TGT_GLB);
    } else if (i < N_CUR + N_TGT_GLB + N_TGT_LOC + N_GLB) {
        int j = i - N_CUR - N_TGT_GLB - N_TGT_LOC;
        int x = glb_coords[3 * j]     - origin[0];
        int y = glb_coords[3 * j + 1] - origin[1];
        int z = glb_coords[3 * j + 2] - origin[2];
        if ((unsigned)x < DIMV && (unsigned)y < DIMV && (unsigned)z < DIMV)
            atomicMax(&w_glb[voxel_of(x, y, z)], j);
    }
}

// Kernel C: persistent grid-stride fused fill (best measured: 55.8 us).
// Touches every output line exactly once — the property that beat all five
// split-structure variants (R5/R8/R9/R10). Plain stores (R6 win). 2048
// blocks x 256 threads; 2 independent chains in flight per thread.
__device__ __forceinline__ void fill_chunk(int c,
                           const int* __restrict__ w_cur,
                           const int* __restrict__ w_glb,
                           const int* __restrict__ w_tgt,
                           const float* __restrict__ cur_values,
                           const float* __restrict__ glb_values,
                           const float* __restrict__ glb_tsdf,
                           const float* __restrict__ loc_tsdf,
                           float* __restrict__ cur_out,
                           float* __restrict__ glb_out,
                           float* __restrict__ tgt_out) {
    int v = c / 6, q = c - v * 6;

    int wc = w_cur[v];
    v4f cval = (v4f){0.f, 0.f, 0.f, 0.f};
    if (wc >= 0) cval = *(const v4f*)(cur_values + (size_t)wc * NCH + q * 4);
    *(v4f*)(cur_out + (size_t)v * NCH + q * 4) = cval;

    int wg = w_glb[v];
    v4f gval = (v4f){0.f, 0.f, 0.f, 0.f};
    if (wg >= 0 && wc >= 0)   // voxel-side occupancy gate (see k_points)
        gval = *(const v4f*)(glb_values + (size_t)wg * NCH + q * 4);
    *(v4f*)(glb_out + (size_t)v * NCH + q * 4) = gval;

    if (q == 0) {
        int wt = w_tgt[v];
        float tval = 1.0f;
        if (wt >= 0) tval = (wt < N_TGT_GLB) ? glb_tsdf[wt] : loc_tsdf[wt - N_TGT_GLB];
        tgt_out[v] = tval;
    }
}

__global__ void __launch_bounds__(256) k_fill_all(
                           const int* __restrict__ w_cur,
                           const int* __restrict__ w_glb,
                           const int* __restrict__ w_tgt,
                           const int* __restrict__ glb_coords,
                           const int* __restrict__ origin,
                           const float* __restrict__ cur_values,
                           const float* __restrict__ glb_values,
                           const float* __restrict__ glb_tsdf,   // [120000]
                           const float* __restrict__ loc_tsdf,   // [100000]
                           float* __restrict__ cur_out,
                           float* __restrict__ glb_out,
                           float* __restrict__ tgt_out,
                           float* __restrict__ valid_out) {
    int tid = blockIdx.x * blockDim.x + threadIdx.x;
    int nthreads = gridDim.x * blockDim.x;

    // per-point global `valid` (needs completed w_cur; rides on first 200k threads)
    if (tid < N_GLB) {
        int x = glb_coords[3 * tid]     - origin[0];
        int y = glb_coords[3 * tid + 1] - origin[1];
        int z = glb_coords[3 * tid + 2] - origin[2];
        bool inb = (unsigned)x < DIMV && (unsigned)y < DIMV && (unsigned)z < DIMV;
        int cx = min(max(x, 0), DIMV - 1);
        int cy = min(max(y, 0), DIMV - 1);
        int cz = min(max(z, 0), DIMV - 1);
        bool valid = inb && (w_cur[voxel_of(cx, cy, cz)] >= 0);   // occ != 0
        valid_out[tid] = valid ? 1.0f : 0.0f;
    }

    // grid-stride over all 16B chunks, 2 independent chains per iteration
    for (int c = tid; c < FILL_CHUNKS; c += 2 * nthreads) {
        fill_chunk(c, w_cur, w_glb, w_tgt, cur_values, glb_values,
                   glb_tsdf, loc_tsdf, cur_out, glb_out, tgt_out);
        int c2 = c + nthreads;
        if (c2 < FILL_CHUNKS)
            fill_chunk(c2, w_cur, w_glb, w_tgt, cur_values, glb_values,
                       glb_tsdf, loc_tsdf, cur_out, glb_out, tgt_out);
    }
}

extern "C" void kernel_launch(void* const* d_in, const int* in_sizes, int n_in,
                              void* d_out, int out_size, void* d_ws, size_t ws_size,
                              hipStream_t stream) {
    const int*   cur_coords   = (const int*)d_in[0];
    const float* cur_values   = (const float*)d_in[1];
    const int*   glb_coords   = (const int*)d_in[2];
    const float* glb_values   = (const float*)d_in[3];
    const int*   tgt_coords_l = (const int*)d_in[4];
    const float* tgt_tsdf_l   = (const float*)d_in[5];
    const int*   tgt_coords_g = (const int*)d_in[6];
    const float* tgt_tsdf_g   = (const float*)d_in[7];
    const int*   rel_origin   = (const int*)d_in[8];

    float* out = (float*)d_out;
    int* w_cur = (int*)d_ws;         // [VOX] winner current (>=0 also = occupancy)
    int* w_glb = w_cur + VOX;        // [VOX] winner global (in-bounds, voxel-gated)
    int* w_tgt = w_glb + VOX;        // [VOX] winner target

    const int T = 256;
    auto blocks = [](int n) { return (n + 255) / 256; };

    // 1: winner init to -1 + coords copy (plain stores -> L2-resident winners)
    k_init<<<blocks(NV4_WS + N_COORD4), T, 0, stream>>>(
        (int*)d_ws, cur_coords, out + OFF_COORDS);

    // 2: ALL point scatters (cur, tgt-g + validt, tgt-l, glb in-bounds)
    k_points<<<blocks(N_CUR + N_TGT_GLB + N_TGT_LOC + N_GLB), T, 0, stream>>>(
        cur_coords, tgt_coords_g, tgt_coords_l, glb_coords, rel_origin,
        w_cur, w_tgt, w_glb, out + OFF_VALIDT);

    // 3: persistent grid-stride fused fill (2048 blocks = full thread capacity)
    k_fill_all<<<2048, T, 0, stream>>>(
        w_cur, w_glb, w_tgt, glb_coords, rel_origin,
        cur_values, glb_values, tgt_tsdf_g, tgt_tsdf_l,
        out + OFF_CURVOL, out + OFF_GLBVOL, out + OFF_TGTVOL, out + OFF_VALID);
}